// Round 10
// baseline (281.856 us; speedup 1.0000x reference)
//
#include <hip/hip_runtime.h>
#include <hip/hip_bf16.h>
#include <stdint.h>

// GCN forward, collapsed to scalar form (W1:[1,16], W2:[16,1] are rank-1).
// R10: exact two-key partition (dst-bucket x src-bucket cells) so that the
// scatter has ZERO per-lane-divergent global loads. R6-R9 pinned k_scat at
// 43-50 us across occupancy/MLP/bin-size changes -> the invariant was the
// 6.4M random val[src] gathers (64 distinct lines per wave-load serialize in
// the CU's TA/L1). Now each scat block caches its 32 KB val slice in LDS
// (sequential) and streams a contiguous record slice; the random accesses
// are LDS reads + LDS atomics.
// Pipeline (10 dispatches, no memset, no global atomics, no CAP overflow):
//   k_cnt   : per-block histogram over NCELL=NB*NQ cells
//   k_scan1 : per-cell exclusive scan over blocks -> bases, totals
//   k_scan2 : exclusive scan over cells -> cellstart
//   k_part  : write rec = (dst&2047)|((src&8191)<<11) to exact positions
//   k_deg   : u16-packed degree bins from records (grid SJ x NB)
//   k_node1 : deg partials -> dinv; dropout1 -> y
//   k_scat  : grid (SJ=2*NQ, NB): cache val[q-slice] in LDS, bins+=cache[..]
//   k_node2 : reduce partials; relu+dropout2+W2 dot -> z2
//   k_scat  : layer 2;  k_final: out = b2 + dinv*sum(partials)
// Dropout reproduces JAX partitionable threefry (split k_i=E(key,(0,i));
// bits = o0^o1 of E(k,(0,j))). Requires N <= 131072 (NCELLMAX/LDS).

#define KEEP_P 0.4f
#define RANGE 2048
#define SHIFT 11
#define MASK 2047
#define QRANGE 8192
#define QSHIFT 13
#define QMASK 8191
#define BPC 512          // cnt/part blocks (scan1 assumes 512 = 2*256)
#define NCELLMAX 1024

__host__ __device__ inline unsigned rotl32(unsigned v, int s) {
  return (v << s) | (v >> (32 - s));
}

__host__ __device__ inline void threefry2x32(unsigned key0, unsigned key1,
                                             unsigned x0, unsigned x1,
                                             unsigned& o0, unsigned& o1) {
  unsigned ks0 = key0, ks1 = key1, ks2 = key0 ^ key1 ^ 0x1BD11BDAu;
  unsigned v0 = x0 + ks0, v1 = x1 + ks1;
#define TF_R(r) { v0 += v1; v1 = rotl32(v1, r); v1 ^= v0; }
  TF_R(13) TF_R(15) TF_R(26) TF_R(6)
  v0 += ks1; v1 += ks2 + 1u;
  TF_R(17) TF_R(29) TF_R(16) TF_R(24)
  v0 += ks2; v1 += ks0 + 2u;
  TF_R(13) TF_R(15) TF_R(26) TF_R(6)
  v0 += ks0; v1 += ks1 + 3u;
  TF_R(17) TF_R(29) TF_R(16) TF_R(24)
  v0 += ks1; v1 += ks2 + 4u;
  TF_R(13) TF_R(15) TF_R(26) TF_R(6)
  v0 += ks2; v1 += ks0 + 5u;
#undef TF_R
  o0 = v0; o1 = v1;
}

__device__ inline float u01_from_bits(unsigned bits) {
  return __uint_as_float((bits >> 9) | 0x3f800000u) - 1.0f;
}

// ---- K1: per-block cell histogram ------------------------------------------
__global__ __launch_bounds__(256) void k_cnt(
    const int* __restrict__ src, const int* __restrict__ dst,
    unsigned* __restrict__ counts, int NCELL, int NQ, int e4, int E) {
  __shared__ unsigned cnt[NCELLMAX];
  const int tid = threadIdx.x;
  for (int c = tid; c < NCELL; c += 256) cnt[c] = 0u;
  __syncthreads();
  const int chunk = (e4 + BPC - 1) / BPC;
  const int j0 = blockIdx.x * chunk, j1 = min(j0 + chunk, e4);
  const int4* d4 = reinterpret_cast<const int4*>(dst);
  const int4* s4 = reinterpret_cast<const int4*>(src);
#define CNT1(d, s) atomicAdd(&cnt[((unsigned)(d) >> SHIFT) * NQ + \
                                  ((unsigned)(s) >> QSHIFT)], 1u);
  for (int j = j0 + tid; j < j1; j += 256) {
    int4 d = d4[j]; int4 s = s4[j];
    CNT1(d.x, s.x) CNT1(d.y, s.y) CNT1(d.z, s.z) CNT1(d.w, s.w)
  }
  if (blockIdx.x == 0) {  // tail when E%4 != 0 (dead for E=6.4M)
    for (int t = e4 * 4 + tid; t < E; t += 256) CNT1(dst[t], src[t])
  }
#undef CNT1
  __syncthreads();
  unsigned* my = counts + (size_t)blockIdx.x * NCELL;
  for (int c = tid; c < NCELL; c += 256) my[c] = cnt[c];
}

// ---- K2: per-cell exclusive scan over 512 blocks ---------------------------
__global__ __launch_bounds__(256) void k_scan1(
    const unsigned* __restrict__ counts, unsigned* __restrict__ bases,
    unsigned* __restrict__ total, int NCELL) {
  __shared__ unsigned sc[256];
  const int c = blockIdx.x, t = threadIdx.x;
  unsigned c0 = counts[(size_t)(2 * t) * NCELL + c];
  unsigned c1 = counts[(size_t)(2 * t + 1) * NCELL + c];
  unsigned s = c0 + c1;
  sc[t] = s;
  __syncthreads();
  for (int ofs = 1; ofs < 256; ofs <<= 1) {
    unsigned v = (t >= ofs) ? sc[t - ofs] : 0u;
    __syncthreads();
    sc[t] += v;
    __syncthreads();
  }
  unsigned excl = sc[t] - s;
  bases[(size_t)(2 * t) * NCELL + c] = excl;
  bases[(size_t)(2 * t + 1) * NCELL + c] = excl + c0;
  if (t == 255) total[c] = sc[255];
}

// ---- K3: exclusive scan over cells -> cellstart ----------------------------
__global__ __launch_bounds__(256) void k_scan2(
    const unsigned* __restrict__ total, unsigned* __restrict__ cellstart,
    int NCELL, int E) {
  __shared__ unsigned sc[256];
  const int t = threadIdx.x;
  unsigned l[4]; unsigned s = 0;
  for (int k = 0; k < 4; ++k) {
    int idx = t * 4 + k;
    unsigned v = (idx < NCELL) ? total[idx] : 0u;
    l[k] = s; s += v;
  }
  sc[t] = s;
  __syncthreads();
  for (int ofs = 1; ofs < 256; ofs <<= 1) {
    unsigned v = (t >= ofs) ? sc[t - ofs] : 0u;
    __syncthreads();
    sc[t] += v;
    __syncthreads();
  }
  unsigned excl = sc[t] - s;
  for (int k = 0; k < 4; ++k) {
    int idx = t * 4 + k;
    if (idx < NCELL) cellstart[idx] = excl + l[k];
  }
  if (t == 255) cellstart[NCELL] = (unsigned)E;
}

// ---- K4: write records to exact cell positions -----------------------------
__global__ __launch_bounds__(256) void k_part(
    const int* __restrict__ src, const int* __restrict__ dst,
    const unsigned* __restrict__ bases, const unsigned* __restrict__ cellstart,
    unsigned* __restrict__ rec, int NCELL, int NQ, int e4, int E) {
  __shared__ unsigned cur[NCELLMAX];
  const int tid = threadIdx.x;
  const unsigned* myb = bases + (size_t)blockIdx.x * NCELL;
  for (int c = tid; c < NCELL; c += 256) cur[c] = cellstart[c] + myb[c];
  __syncthreads();
  const int chunk = (e4 + BPC - 1) / BPC;
  const int j0 = blockIdx.x * chunk, j1 = min(j0 + chunk, e4);
  const int4* d4 = reinterpret_cast<const int4*>(dst);
  const int4* s4 = reinterpret_cast<const int4*>(src);
#define PART1(d, s) { unsigned ud = (unsigned)(d), us = (unsigned)(s); \
    unsigned cell = (ud >> SHIFT) * NQ + (us >> QSHIFT); \
    unsigned pos = atomicAdd(&cur[cell], 1u); \
    rec[pos] = (ud & MASK) | ((us & QMASK) << SHIFT); }
  for (int j = j0 + tid; j < j1; j += 256) {
    int4 d = d4[j]; int4 s = s4[j];
    PART1(d.x, s.x) PART1(d.y, s.y) PART1(d.z, s.z) PART1(d.w, s.w)
  }
  if (blockIdx.x == 0) {  // tail when E%4 != 0 (dead for E=6.4M)
    for (int t = e4 * 4 + tid; t < E; t += 256) PART1(dst[t], src[t])
  }
#undef PART1
}

// ---- K5: degree from records, u16-packed bins ------------------------------
__global__ __launch_bounds__(256) void k_deg(
    const unsigned* __restrict__ rec, const unsigned* __restrict__ cellstart,
    unsigned short* __restrict__ degpart, int NB, int NQ, int SJ) {
  __shared__ unsigned bins[RANGE / 2];  // 4 KB
  const int tid = threadIdx.x;
  const int j = blockIdx.x, p = blockIdx.y;
  for (int i = tid; i < RANGE / 2; i += 256) bins[i] = 0u;
  __syncthreads();
  const int s0 = (int)cellstart[p * NQ], s1 = (int)cellstart[(p + 1) * NQ];
  const int len = s1 - s0;
  const int a = s0 + (int)((long)len * j / SJ);
  const int b = s0 + (int)((long)len * (j + 1) / SJ);
#define DEG1(v) { unsigned r = (v) & MASK; \
    atomicAdd(&bins[r >> 1], 1u << ((r & 1) * 16)); }
  int i = a + tid;
  for (; i + 768 < b; i += 1024) {
    unsigned v0 = rec[i], v1 = rec[i + 256], v2 = rec[i + 512], v3 = rec[i + 768];
    DEG1(v0) DEG1(v1) DEG1(v2) DEG1(v3)
  }
  for (; i < b; i += 256) DEG1(rec[i])
#undef DEG1
  __syncthreads();
  unsigned* my32 = (unsigned*)(degpart + ((size_t)j * NB + p) * RANGE);
  for (int i2 = tid; i2 < RANGE / 2; i2 += 256) my32[i2] = bins[i2];
}

// ---- K6: reduce deg partials -> dinv; dropout1 -> y ------------------------
__global__ __launch_bounds__(256) void k_node1(
    const float* __restrict__ x, const unsigned short* __restrict__ degpart,
    float* __restrict__ dinv, float* __restrict__ y,
    int NB, int SJ, int n, unsigned k1a, unsigned k1b) {
  int i = blockIdx.x * blockDim.x + threadIdx.x;
  if (i >= n) return;
  const int p = i >> SHIFT, r = i & MASK;
  unsigned d = 0;
  for (int j = 0; j < SJ; ++j) d += degpart[((size_t)j * NB + p) * RANGE + r];
  float di = (d > 0) ? (1.0f / sqrtf((float)d)) : 0.0f;
  dinv[i] = di;
  unsigned o0, o1;
  threefry2x32(k1a, k1b, 0u, (unsigned)i, o0, o1);
  float u = u01_from_bits(o0 ^ o1);   // partitionable 32-bit bits = out0 ^ out1
  float xd = (u < KEEP_P) ? (x[i] / KEEP_P) : 0.0f;
  y[i] = xd * di;
}

// ---- K7/K9: scatter with LDS val cache (no divergent global loads) ---------
__global__ __launch_bounds__(256) void k_scat(
    const unsigned* __restrict__ rec, const unsigned* __restrict__ cellstart,
    const float* __restrict__ val, float* __restrict__ part,
    int NB, int NQ, int N) {
  __shared__ float cache[QRANGE];  // 32 KB
  __shared__ float bins[RANGE];    // 8 KB
  const int tid = threadIdx.x;
  const int j = blockIdx.x, p = blockIdx.y;
  const int q = j >> 1, h = j & 1;
  const int g0 = q * QRANGE;
  const int lim = min(QRANGE, N - g0);
  for (int i = tid; i < lim; i += 256) cache[i] = val[g0 + i];
  for (int i = tid; i < RANGE; i += 256) bins[i] = 0.0f;
  __syncthreads();
  const int s0 = (int)cellstart[p * NQ + q], s1 = (int)cellstart[p * NQ + q + 1];
  const int half = (s1 - s0) >> 1;
  const int a = s0 + h * half;
  const int b = h ? s1 : s0 + half;
  int i = a + tid;
  for (; i + 768 < b; i += 1024) {
    unsigned v0 = rec[i], v1 = rec[i + 256], v2 = rec[i + 512], v3 = rec[i + 768];
    float f0 = cache[v0 >> SHIFT], f1 = cache[v1 >> SHIFT];
    float f2 = cache[v2 >> SHIFT], f3 = cache[v3 >> SHIFT];
    atomicAdd(&bins[v0 & MASK], f0);
    atomicAdd(&bins[v1 & MASK], f1);
    atomicAdd(&bins[v2 & MASK], f2);
    atomicAdd(&bins[v3 & MASK], f3);
  }
  for (; i < b; i += 256) {
    unsigned v = rec[i];
    atomicAdd(&bins[v & MASK], cache[v >> SHIFT]);
  }
  __syncthreads();
  float* my = part + ((size_t)j * NB + p) * RANGE;
  for (int i2 = tid; i2 < RANGE; i2 += 256) my[i2] = bins[i2];
}

// ---- K8: reduce s partials; layer1 epilogue + relu + dropout2 + W2 dot -----
__global__ __launch_bounds__(256) void k_node2(
    const float* __restrict__ part, const float* __restrict__ dinv,
    const float* __restrict__ W1, const float* __restrict__ b1,
    const float* __restrict__ W2, float* __restrict__ z2,
    int NB, int SJ, int n, unsigned k2a, unsigned k2b) {
  int i = blockIdx.x * blockDim.x + threadIdx.x;
  if (i >= n) return;
  const int p = i >> SHIFT, r = i & MASK;
  float s = 0.0f;
  for (int j = 0; j < SJ; ++j) s += part[((size_t)j * NB + p) * RANGE + r];
  float t = s * dinv[i];
  float z = 0.0f;
  unsigned base = (unsigned)i * 16u;
#pragma unroll
  for (int c = 0; c < 16; ++c) {
    float h = W1[c] * t + b1[c];
    h = fmaxf(h, 0.0f);
    unsigned o0, o1;
    threefry2x32(k2a, k2b, 0u, base + (unsigned)c, o0, o1);
    float u = u01_from_bits(o0 ^ o1);
    float hd = (u < KEEP_P) ? (h / KEEP_P) : 0.0f;
    z += hd * W2[c];
  }
  z2[i] = z * dinv[i];   // dinv[dst] factor applied in k_final
}

// ---- K10: final combine: out = b2 + dinv * sum(partials) -------------------
__global__ __launch_bounds__(256) void k_final(
    const float* __restrict__ part, const float* __restrict__ dinv,
    const float* __restrict__ b2, float* __restrict__ out,
    int NB, int SJ, int n) {
  int i = blockIdx.x * blockDim.x + threadIdx.x;
  if (i >= n) return;
  const int p = i >> SHIFT, r = i & MASK;
  float s = 0.0f;
  for (int j = 0; j < SJ; ++j) s += part[((size_t)j * NB + p) * RANGE + r];
  out[i] = b2[0] + dinv[i] * s;
}

extern "C" void kernel_launch(void* const* d_in, const int* in_sizes, int n_in,
                              void* d_out, int out_size, void* d_ws, size_t ws_size,
                              hipStream_t stream) {
  const float* x  = (const float*)d_in[0];
  const int* edge = (const int*)d_in[1];   // [2, E] int32
  const float* W1 = (const float*)d_in[2]; // [1,16]
  const float* b1 = (const float*)d_in[3]; // [16]
  const float* W2 = (const float*)d_in[4]; // [16,1]
  const float* b2 = (const float*)d_in[5]; // [1]
  float* out = (float*)d_out;              // [N,1] f32

  const int N = in_sizes[0];
  const int E = in_sizes[1] / 2;
  const int* src = edge;
  const int* dst = edge + E;

  const int NP = (N + 255) & ~255;
  const int NB = (N + RANGE - 1) / RANGE;    // 49 for N=100K
  const int NQ = (N + QRANGE - 1) / QRANGE;  // 13 for N=100K
  const int NCELL = NB * NQ;                 // 637 (<= NCELLMAX)
  const int SJ = 2 * NQ;                     // 26 scatter/deg slices

  // ws layout (aligned 256B): counts[BPC][NCELL], bases[BPC][NCELL],
  // total[NCELL], cellstart[NCELL+1], rec[E],
  // part[SJ][NB][RANGE] f32 (aliases degpart u16), dinv, y, z2
  char* w = (char*)d_ws;
  auto align256 = [](char* p) {
    return (char*)(((uintptr_t)p + 255) & ~(uintptr_t)255);
  };
  unsigned* counts = (unsigned*)w;  w = align256(w + (size_t)BPC * NCELL * 4);
  unsigned* bases  = (unsigned*)w;  w = align256(w + (size_t)BPC * NCELL * 4);
  unsigned* total  = (unsigned*)w;  w = align256(w + (size_t)NCELL * 4);
  unsigned* cellst = (unsigned*)w;  w = align256(w + (size_t)(NCELL + 1) * 4);
  unsigned* rec    = (unsigned*)w;  w = align256(w + (size_t)E * 4);
  float* part_f = (float*)w;
  unsigned short* degpart = (unsigned short*)w;  // aliased (deg ends first)
  w = align256(w + (size_t)SJ * NB * RANGE * 4);
  float* dinv = (float*)w;
  float* y    = dinv + NP;
  float* z2   = y + NP;

  // Dropout keys: foldlike split(key(42)) under partitionable threefry.
  unsigned k1a, k1b, k2a, k2b;
  threefry2x32(0u, 42u, 0u, 0u, k1a, k1b);
  threefry2x32(0u, 42u, 0u, 1u, k2a, k2b);

  const int e4 = E >> 2;
  const int gN = (N + 255) / 256;

  k_cnt  <<<BPC, 256, 0, stream>>>(src, dst, counts, NCELL, NQ, e4, E);
  k_scan1<<<NCELL, 256, 0, stream>>>(counts, bases, total, NCELL);
  k_scan2<<<1, 256, 0, stream>>>(total, cellst, NCELL, E);
  k_part <<<BPC, 256, 0, stream>>>(src, dst, bases, cellst, rec, NCELL, NQ, e4, E);
  k_deg  <<<dim3(SJ, NB), 256, 0, stream>>>(rec, cellst, degpart, NB, NQ, SJ);
  k_node1<<<gN, 256, 0, stream>>>(x, degpart, dinv, y, NB, SJ, N, k1a, k1b);
  k_scat <<<dim3(SJ, NB), 256, 0, stream>>>(rec, cellst, y, part_f, NB, NQ, N);
  k_node2<<<gN, 256, 0, stream>>>(part_f, dinv, W1, b1, W2, z2, NB, SJ, N, k2a, k2b);
  k_scat <<<dim3(SJ, NB), 256, 0, stream>>>(rec, cellst, z2, part_f, NB, NQ, N);
  k_final<<<gN, 256, 0, stream>>>(part_f, dinv, b2, out, NB, SJ, N);
}

// Round 11
// 260.244 us; speedup vs baseline: 1.0830x; 1.0830x over previous
//
#include <hip/hip_runtime.h>
#include <hip/hip_bf16.h>
#include <stdint.h>

// GCN forward, collapsed to scalar form (W1:[1,16], W2:[16,1] are rank-1).
// R11: two-key cell partition (R10) with TILE-SORTED COALESCED writes (R9's
// trick, upsized). R10's k_part wrote each record to a random global cell
// position -> WRITE_SIZE 143 MB (22 B/edge partial lines), 60 us, total
// regressed. Now k_part stages 8192-edge tiles in LDS sorted by cell and
// writes cell-contiguous runs (~13 recs = 52 B) at exact positions from
// per-block cell cursors. k_scat: one block per (p,q) cell: val q-slice
// cached in LDS (32 KB, sequential), bins 8 KB; per edge = streamed record
// + LDS read + LDS atomic; ZERO divergent global loads anywhere.
// Pipeline: cnt, scan1, scan2, part, deg, node1, scat, node2, scat, final.
// No global atomics (R2-R4: gfx950 global atomic RMW is memory-side ~20G/s).
// Dropout = JAX partitionable threefry (split k_i=E(key,(0,i)); bits=o0^o1).
// Requires N <= 131072 (NCELLMAX=1024, cellid u16... NCELL<=1024).

#define KEEP_P 0.4f
#define RANGE 2048
#define SHIFT 11
#define MASK 2047
#define QRANGE 8192
#define QSHIFT 13
#define QMASK 8191
#define BPC 512          // cnt/part blocks (scan1 assumes 512 = 2*256)
#define NCELLMAX 1024
#define TILE 8192
#define TILE4 (TILE / 4)

__host__ __device__ inline unsigned rotl32(unsigned v, int s) {
  return (v << s) | (v >> (32 - s));
}

__host__ __device__ inline void threefry2x32(unsigned key0, unsigned key1,
                                             unsigned x0, unsigned x1,
                                             unsigned& o0, unsigned& o1) {
  unsigned ks0 = key0, ks1 = key1, ks2 = key0 ^ key1 ^ 0x1BD11BDAu;
  unsigned v0 = x0 + ks0, v1 = x1 + ks1;
#define TF_R(r) { v0 += v1; v1 = rotl32(v1, r); v1 ^= v0; }
  TF_R(13) TF_R(15) TF_R(26) TF_R(6)
  v0 += ks1; v1 += ks2 + 1u;
  TF_R(17) TF_R(29) TF_R(16) TF_R(24)
  v0 += ks2; v1 += ks0 + 2u;
  TF_R(13) TF_R(15) TF_R(26) TF_R(6)
  v0 += ks0; v1 += ks1 + 3u;
  TF_R(17) TF_R(29) TF_R(16) TF_R(24)
  v0 += ks1; v1 += ks2 + 4u;
  TF_R(13) TF_R(15) TF_R(26) TF_R(6)
  v0 += ks2; v1 += ks0 + 5u;
#undef TF_R
  o0 = v0; o1 = v1;
}

__device__ inline float u01_from_bits(unsigned bits) {
  return __uint_as_float((bits >> 9) | 0x3f800000u) - 1.0f;
}

// ---- K1: per-block cell histogram ------------------------------------------
__global__ __launch_bounds__(256) void k_cnt(
    const int* __restrict__ src, const int* __restrict__ dst,
    unsigned* __restrict__ counts, int NCELL, int NQ, int e4, int E) {
  __shared__ unsigned cnt[NCELLMAX];
  const int tid = threadIdx.x;
  for (int c = tid; c < NCELL; c += 256) cnt[c] = 0u;
  __syncthreads();
  const int chunk = (e4 + BPC - 1) / BPC;
  const int j0 = blockIdx.x * chunk, j1 = min(j0 + chunk, e4);
  const int4* d4 = reinterpret_cast<const int4*>(dst);
  const int4* s4 = reinterpret_cast<const int4*>(src);
#define CNT1(d, s) atomicAdd(&cnt[((unsigned)(d) >> SHIFT) * NQ + \
                                  ((unsigned)(s) >> QSHIFT)], 1u);
  for (int j = j0 + tid; j < j1; j += 256) {
    int4 d = d4[j]; int4 s = s4[j];
    CNT1(d.x, s.x) CNT1(d.y, s.y) CNT1(d.z, s.z) CNT1(d.w, s.w)
  }
  if (blockIdx.x == 0) {  // tail when E%4 != 0 (dead for E=6.4M)
    for (int t = e4 * 4 + tid; t < E; t += 256) CNT1(dst[t], src[t])
  }
#undef CNT1
  __syncthreads();
  unsigned* my = counts + (size_t)blockIdx.x * NCELL;
  for (int c = tid; c < NCELL; c += 256) my[c] = cnt[c];
}

// ---- K2: per-cell exclusive scan over 512 blocks ---------------------------
__global__ __launch_bounds__(256) void k_scan1(
    const unsigned* __restrict__ counts, unsigned* __restrict__ bases,
    unsigned* __restrict__ total, int NCELL) {
  __shared__ unsigned sc[256];
  const int c = blockIdx.x, t = threadIdx.x;
  unsigned c0 = counts[(size_t)(2 * t) * NCELL + c];
  unsigned c1 = counts[(size_t)(2 * t + 1) * NCELL + c];
  unsigned s = c0 + c1;
  sc[t] = s;
  __syncthreads();
  for (int ofs = 1; ofs < 256; ofs <<= 1) {
    unsigned v = (t >= ofs) ? sc[t - ofs] : 0u;
    __syncthreads();
    sc[t] += v;
    __syncthreads();
  }
  unsigned excl = sc[t] - s;
  bases[(size_t)(2 * t) * NCELL + c] = excl;
  bases[(size_t)(2 * t + 1) * NCELL + c] = excl + c0;
  if (t == 255) total[c] = sc[255];
}

// ---- K3: exclusive scan over cells -> cellstart ----------------------------
__global__ __launch_bounds__(256) void k_scan2(
    const unsigned* __restrict__ total, unsigned* __restrict__ cellstart,
    int NCELL, int E) {
  __shared__ unsigned sc[256];
  const int t = threadIdx.x;
  unsigned l[4]; unsigned s = 0;
  for (int k = 0; k < 4; ++k) {
    int idx = t * 4 + k;
    unsigned v = (idx < NCELL) ? total[idx] : 0u;
    l[k] = s; s += v;
  }
  sc[t] = s;
  __syncthreads();
  for (int ofs = 1; ofs < 256; ofs <<= 1) {
    unsigned v = (t >= ofs) ? sc[t - ofs] : 0u;
    __syncthreads();
    sc[t] += v;
    __syncthreads();
  }
  unsigned excl = sc[t] - s;
  for (int k = 0; k < 4; ++k) {
    int idx = t * 4 + k;
    if (idx < NCELL) cellstart[idx] = excl + l[k];
  }
  if (t == 255) cellstart[NCELL] = (unsigned)E;
}

// ---- K4: tile-sorted partition to exact cell positions ---------------------
__global__ __launch_bounds__(256) void k_part(
    const int* __restrict__ src, const int* __restrict__ dst,
    const unsigned* __restrict__ bases, const unsigned* __restrict__ cellstart,
    unsigned* __restrict__ rec, int NCELL, int NQ, int e4, int E) {
  __shared__ unsigned stage[TILE];          // 32 KB
  __shared__ unsigned short cellid[TILE];   // 16 KB
  __shared__ unsigned hist[NCELLMAX], off[NCELLMAX], tscan[NCELLMAX];
  __shared__ unsigned tbase[NCELLMAX], blkcur[NCELLMAX];
  __shared__ unsigned ssum[256];
  const int tid = threadIdx.x;
  const unsigned* myb = bases + (size_t)blockIdx.x * NCELL;
  for (int c = tid; c < NCELL; c += 256) blkcur[c] = cellstart[c] + myb[c];
  const int chunk = (e4 + BPC - 1) / BPC;
  const int j0 = blockIdx.x * chunk, j1 = min(j0 + chunk, e4);
  const int4* d4 = reinterpret_cast<const int4*>(dst);
  const int4* s4 = reinterpret_cast<const int4*>(src);
  const int K = (NCELL + 255) / 256;  // <= 4

  for (int t0 = j0; t0 < j1; t0 += TILE4) {
    __syncthreads();  // protects prev write-out & blkcur init
    for (int c = tid; c < NCELL; c += 256) hist[c] = 0u;
    __syncthreads();
    const int tcnt = min(TILE4, j1 - t0);
    // A: count
    for (int jj = tid; jj < tcnt; jj += 256) {
      int4 d = d4[t0 + jj]; int4 s = s4[t0 + jj];
      atomicAdd(&hist[((unsigned)d.x >> SHIFT) * NQ + ((unsigned)s.x >> QSHIFT)], 1u);
      atomicAdd(&hist[((unsigned)d.y >> SHIFT) * NQ + ((unsigned)s.y >> QSHIFT)], 1u);
      atomicAdd(&hist[((unsigned)d.z >> SHIFT) * NQ + ((unsigned)s.z >> QSHIFT)], 1u);
      atomicAdd(&hist[((unsigned)d.w >> SHIFT) * NQ + ((unsigned)s.w >> QSHIFT)], 1u);
    }
    __syncthreads();
    // B: block-exclusive-scan over NCELL cells
    unsigned l[4]; unsigned s = 0;
    for (int k = 0; k < K; ++k) {
      int c = tid * K + k;
      unsigned v = (c < NCELL) ? hist[c] : 0u;
      l[k] = s; s += v;
    }
    ssum[tid] = s;
    __syncthreads();
    for (int ofs = 1; ofs < 256; ofs <<= 1) {
      unsigned v = (tid >= ofs) ? ssum[tid - ofs] : 0u;
      __syncthreads();
      ssum[tid] += v;
      __syncthreads();
    }
    unsigned excl = ssum[tid] - s;
    for (int k = 0; k < K; ++k) {
      int c = tid * K + k;
      if (c < NCELL) {
        unsigned e = excl + l[k];
        off[c] = e; tscan[c] = e;
        tbase[c] = blkcur[c];
        blkcur[c] += hist[c];
      }
    }
    __syncthreads();
    // C: stage sorted-by-cell (re-read edges; L1/L2 hit)
    for (int jj = tid; jj < tcnt; jj += 256) {
      int4 d = d4[t0 + jj]; int4 s2 = s4[t0 + jj];
#define STG1(dd, ss) { unsigned ud = (unsigned)(dd), us = (unsigned)(ss); \
      unsigned cell = (ud >> SHIFT) * NQ + (us >> QSHIFT); \
      unsigned pos = atomicAdd(&off[cell], 1u); \
      stage[pos] = (ud & MASK) | ((us & QMASK) << SHIFT); \
      cellid[pos] = (unsigned short)cell; }
      STG1(d.x, s2.x) STG1(d.y, s2.y) STG1(d.z, s2.z) STG1(d.w, s2.w)
#undef STG1
    }
    __syncthreads();
    // D: write out cell-contiguous runs at exact global positions
    const int tc = 4 * tcnt;
    for (int i = tid; i < tc; i += 256) {
      unsigned c = cellid[i];
      rec[tbase[c] + ((unsigned)i - tscan[c])] = stage[i];
    }
  }
  __syncthreads();
  if (blockIdx.x == 0) {  // tail when E%4 != 0 (dead for E=6.4M)
    for (int t = e4 * 4 + tid; t < E; t += 256) {
      unsigned ud = (unsigned)dst[t], us = (unsigned)src[t];
      unsigned cell = (ud >> SHIFT) * NQ + (us >> QSHIFT);
      unsigned pos = atomicAdd(&blkcur[cell], 1u);
      rec[pos] = (ud & MASK) | ((us & QMASK) << SHIFT);
    }
  }
}

// ---- K5: degree from records, u16-packed bins ------------------------------
__global__ __launch_bounds__(256) void k_deg(
    const unsigned* __restrict__ rec, const unsigned* __restrict__ cellstart,
    unsigned short* __restrict__ degpart, int NB, int NQ, int SJ) {
  __shared__ unsigned bins[RANGE / 2];  // 4 KB
  const int tid = threadIdx.x;
  const int j = blockIdx.x, p = blockIdx.y;
  for (int i = tid; i < RANGE / 2; i += 256) bins[i] = 0u;
  __syncthreads();
  const int s0 = (int)cellstart[p * NQ], s1 = (int)cellstart[(p + 1) * NQ];
  const int len = s1 - s0;
  const int a = s0 + (int)((long)len * j / SJ);
  const int b = s0 + (int)((long)len * (j + 1) / SJ);
#define DEG1(v) { unsigned r = (v) & MASK; \
    atomicAdd(&bins[r >> 1], 1u << ((r & 1) * 16)); }
  int i = a + tid;
  for (; i + 768 < b; i += 1024) {
    unsigned v0 = rec[i], v1 = rec[i + 256], v2 = rec[i + 512], v3 = rec[i + 768];
    DEG1(v0) DEG1(v1) DEG1(v2) DEG1(v3)
  }
  for (; i < b; i += 256) DEG1(rec[i])
#undef DEG1
  __syncthreads();
  unsigned* my32 = (unsigned*)(degpart + ((size_t)j * NB + p) * RANGE);
  for (int i2 = tid; i2 < RANGE / 2; i2 += 256) my32[i2] = bins[i2];
}

// ---- K6: reduce deg partials -> dinv; dropout1 -> y ------------------------
__global__ __launch_bounds__(256) void k_node1(
    const float* __restrict__ x, const unsigned short* __restrict__ degpart,
    float* __restrict__ dinv, float* __restrict__ y,
    int NB, int SJ, int n, unsigned k1a, unsigned k1b) {
  int i = blockIdx.x * blockDim.x + threadIdx.x;
  if (i >= n) return;
  const int p = i >> SHIFT, r = i & MASK;
  unsigned d = 0;
  for (int j = 0; j < SJ; ++j) d += degpart[((size_t)j * NB + p) * RANGE + r];
  float di = (d > 0) ? (1.0f / sqrtf((float)d)) : 0.0f;
  dinv[i] = di;
  unsigned o0, o1;
  threefry2x32(k1a, k1b, 0u, (unsigned)i, o0, o1);
  float u = u01_from_bits(o0 ^ o1);   // partitionable 32-bit bits = out0 ^ out1
  float xd = (u < KEEP_P) ? (x[i] / KEEP_P) : 0.0f;
  y[i] = xd * di;
}

// ---- K7/K9: per-cell scatter with LDS val cache ----------------------------
__global__ __launch_bounds__(256) void k_scat(
    const unsigned* __restrict__ rec, const unsigned* __restrict__ cellstart,
    const float* __restrict__ val, float* __restrict__ part,
    int NB, int NQ, int N) {
  __shared__ float cache[QRANGE];  // 32 KB
  __shared__ float bins[RANGE];    // 8 KB
  const int tid = threadIdx.x;
  const int q = blockIdx.x, p = blockIdx.y;
  const int g0 = q * QRANGE;
  const int lim = min(QRANGE, N - g0);
  for (int i = tid; i < lim; i += 256) cache[i] = val[g0 + i];
  for (int i = tid; i < RANGE; i += 256) bins[i] = 0.0f;
  __syncthreads();
  const int s0 = (int)cellstart[p * NQ + q], s1 = (int)cellstart[p * NQ + q + 1];
  int i = s0 + tid;
  for (; i + 768 < s1; i += 1024) {
    unsigned v0 = rec[i], v1 = rec[i + 256], v2 = rec[i + 512], v3 = rec[i + 768];
    float f0 = cache[v0 >> SHIFT], f1 = cache[v1 >> SHIFT];
    float f2 = cache[v2 >> SHIFT], f3 = cache[v3 >> SHIFT];
    atomicAdd(&bins[v0 & MASK], f0);
    atomicAdd(&bins[v1 & MASK], f1);
    atomicAdd(&bins[v2 & MASK], f2);
    atomicAdd(&bins[v3 & MASK], f3);
  }
  for (; i < s1; i += 256) {
    unsigned v = rec[i];
    atomicAdd(&bins[v & MASK], cache[v >> SHIFT]);
  }
  __syncthreads();
  float* my = part + ((size_t)q * NB + p) * RANGE;
  for (int i2 = tid; i2 < RANGE; i2 += 256) my[i2] = bins[i2];
}

// ---- K8: reduce s partials; layer1 epilogue + relu + dropout2 + W2 dot -----
__global__ __launch_bounds__(256) void k_node2(
    const float* __restrict__ part, const float* __restrict__ dinv,
    const float* __restrict__ W1, const float* __restrict__ b1,
    const float* __restrict__ W2, float* __restrict__ z2,
    int NB, int NQ, int n, unsigned k2a, unsigned k2b) {
  int i = blockIdx.x * blockDim.x + threadIdx.x;
  if (i >= n) return;
  const int p = i >> SHIFT, r = i & MASK;
  float s = 0.0f;
  for (int q = 0; q < NQ; ++q) s += part[((size_t)q * NB + p) * RANGE + r];
  float t = s * dinv[i];
  float z = 0.0f;
  unsigned base = (unsigned)i * 16u;
#pragma unroll
  for (int c = 0; c < 16; ++c) {
    float h = W1[c] * t + b1[c];
    h = fmaxf(h, 0.0f);
    unsigned o0, o1;
    threefry2x32(k2a, k2b, 0u, base + (unsigned)c, o0, o1);
    float u = u01_from_bits(o0 ^ o1);
    float hd = (u < KEEP_P) ? (h / KEEP_P) : 0.0f;
    z += hd * W2[c];
  }
  z2[i] = z * dinv[i];   // dinv[dst] factor applied in k_final
}

// ---- K10: final combine: out = b2 + dinv * sum(partials) -------------------
__global__ __launch_bounds__(256) void k_final(
    const float* __restrict__ part, const float* __restrict__ dinv,
    const float* __restrict__ b2, float* __restrict__ out,
    int NB, int NQ, int n) {
  int i = blockIdx.x * blockDim.x + threadIdx.x;
  if (i >= n) return;
  const int p = i >> SHIFT, r = i & MASK;
  float s = 0.0f;
  for (int q = 0; q < NQ; ++q) s += part[((size_t)q * NB + p) * RANGE + r];
  out[i] = b2[0] + dinv[i] * s;
}

extern "C" void kernel_launch(void* const* d_in, const int* in_sizes, int n_in,
                              void* d_out, int out_size, void* d_ws, size_t ws_size,
                              hipStream_t stream) {
  const float* x  = (const float*)d_in[0];
  const int* edge = (const int*)d_in[1];   // [2, E] int32
  const float* W1 = (const float*)d_in[2]; // [1,16]
  const float* b1 = (const float*)d_in[3]; // [16]
  const float* W2 = (const float*)d_in[4]; // [16,1]
  const float* b2 = (const float*)d_in[5]; // [1]
  float* out = (float*)d_out;              // [N,1] f32

  const int N = in_sizes[0];
  const int E = in_sizes[1] / 2;
  const int* src = edge;
  const int* dst = edge + E;

  const int NP = (N + 255) & ~255;
  const int NB = (N + RANGE - 1) / RANGE;    // 49 for N=100K
  const int NQ = (N + QRANGE - 1) / QRANGE;  // 13 for N=100K
  const int NCELL = NB * NQ;                 // 637 (<= NCELLMAX)
  const int DSJ = 2 * NQ;                    // 26 deg slices

  // ws layout (256B-aligned): counts[BPC][NCELL], bases[BPC][NCELL],
  // total[NCELL], cellstart[NCELL+1], rec[E],
  // part[NQ][NB][RANGE] f32 (aliases degpart[DSJ][NB][RANGE] u16), dinv,y,z2
  char* w = (char*)d_ws;
  auto align256 = [](char* p) {
    return (char*)(((uintptr_t)p + 255) & ~(uintptr_t)255);
  };
  unsigned* counts = (unsigned*)w;  w = align256(w + (size_t)BPC * NCELL * 4);
  unsigned* bases  = (unsigned*)w;  w = align256(w + (size_t)BPC * NCELL * 4);
  unsigned* total  = (unsigned*)w;  w = align256(w + (size_t)NCELL * 4);
  unsigned* cellst = (unsigned*)w;  w = align256(w + (size_t)(NCELL + 1) * 4);
  unsigned* rec    = (unsigned*)w;  w = align256(w + (size_t)E * 4);
  float* part_f = (float*)w;
  unsigned short* degpart = (unsigned short*)w;  // aliased (deg ends first)
  size_t part_bytes = (size_t)NQ * NB * RANGE * 4;
  size_t deg_bytes  = (size_t)DSJ * NB * RANGE * 2;
  w = align256(w + (part_bytes > deg_bytes ? part_bytes : deg_bytes));
  float* dinv = (float*)w;
  float* y    = dinv + NP;
  float* z2   = y + NP;

  // Dropout keys: foldlike split(key(42)) under partitionable threefry.
  unsigned k1a, k1b, k2a, k2b;
  threefry2x32(0u, 42u, 0u, 0u, k1a, k1b);
  threefry2x32(0u, 42u, 0u, 1u, k2a, k2b);

  const int e4 = E >> 2;
  const int gN = (N + 255) / 256;

  k_cnt  <<<BPC, 256, 0, stream>>>(src, dst, counts, NCELL, NQ, e4, E);
  k_scan1<<<NCELL, 256, 0, stream>>>(counts, bases, total, NCELL);
  k_scan2<<<1, 256, 0, stream>>>(total, cellst, NCELL, E);
  k_part <<<BPC, 256, 0, stream>>>(src, dst, bases, cellst, rec, NCELL, NQ, e4, E);
  k_deg  <<<dim3(DSJ, NB), 256, 0, stream>>>(rec, cellst, degpart, NB, NQ, DSJ);
  k_node1<<<gN, 256, 0, stream>>>(x, degpart, dinv, y, NB, DSJ, N, k1a, k1b);
  k_scat <<<dim3(NQ, NB), 256, 0, stream>>>(rec, cellst, y, part_f, NB, NQ, N);
  k_node2<<<gN, 256, 0, stream>>>(part_f, dinv, W1, b1, W2, z2, NB, NQ, N, k2a, k2b);
  k_scat <<<dim3(NQ, NB), 256, 0, stream>>>(rec, cellst, z2, part_f, NB, NQ, N);
  k_final<<<gN, 256, 0, stream>>>(part_f, dinv, b2, out, NB, NQ, N);
}